// Round 5
// baseline (315.080 us; speedup 1.0000x reference)
//
#include <hip/hip_runtime.h>
#include <hip/hip_bf16.h>

#define N_ 64
#define C_ 512
#define L_ 784
#define K_ 64
#define EPS_ 1e-12f

typedef unsigned short u16;

__device__ __forceinline__ float bf2f(u16 h) {
    return __uint_as_float(((unsigned int)h) << 16);
}
__device__ __forceinline__ u16 f2bf(float f) {
    unsigned int u = __float_as_uint(f);
    u += 0x7fffu + ((u >> 16) & 1u);
    return (u16)(u >> 16);
}

// ---------------------------------------------------------------------------
// Dtype sniffer — vote on the LOW u16 of each u32 of x:
//  - bf16 storage: low u16 is a valid bf16 of N(0,1) -> ~64/64 votes
//  - raw fp32: bits 7..14 are middle mantissa bits -> ~13/64 votes
//  - fp32 holding bf16-rounded values: low16 == 0 -> 0 votes
// flag = 1 -> fp32 storage (fp32 out), 0 -> bf16 storage (bf16 out).
// R4 evidence: this data is fp32 (R2==R4 bitwise; R1 bf16-cast gave NaN).
// ---------------------------------------------------------------------------
__global__ void kFlag(const unsigned* __restrict__ x, int* __restrict__ flag) {
    int lane = threadIdx.x;  // 64 threads
    unsigned v = x[lane];
    int elo = (v >> 7) & 0xFF;
    int nz  = (v & 0xFFFFu) != 0u;
    int vote_bf16 = (nz && elo >= 100 && elo <= 150) ? 1 : 0;
    unsigned long long m = __ballot(vote_bf16 != 0);
    if (lane == 0) *flag = (__popcll(m) >= 40) ? 0 : 1;
}

// ---------------------------------------------------------------------------
// Kernel A: logits = conv_w @ x[n] (64k x 112l tile), softmax over k,
// write a as u16 fixed-point (a*65535) + per-(n,lt) partial asum.
// grid (7, Gn). block 256. Thread tile 4k x 7l.
// ---------------------------------------------------------------------------
template <bool F32>
__global__ __launch_bounds__(256) void kA(const void* __restrict__ xv,
                                          const void* __restrict__ wv,
                                          const int* __restrict__ flag,
                                          int n0,
                                          u16* __restrict__ a_q,
                                          float* __restrict__ asum_part) {
    if (*flag != (F32 ? 1 : 0)) return;
    __shared__ union {
        struct { float wt[64 * 68]; float xs[64 * 112]; } g;  // wt[c][k], xs[c][l]
        float sl[64 * 113];                                   // sl[k][l] post-GEMM
    } sm;
    const int t  = threadIdx.x;
    const int ln = blockIdx.y;          // local n within group
    const int n  = n0 + ln;             // global n
    const int lt = blockIdx.x;
    const int l0 = lt * 112;
    const int tx = t & 15, ty = t >> 4;

    float acc[4][7];
#pragma unroll
    for (int i = 0; i < 4; i++)
#pragma unroll
        for (int j = 0; j < 7; j++) acc[i][j] = 0.f;

    const size_t xoff = (size_t)n * (C_ * L_) + l0;

    for (int cc = 0; cc < 8; ++cc) {
        const int c0 = cc * 64;
#pragma unroll
        for (int i = 0; i < 8; i++) {
            int e = t + 256 * i;          // 0..2047 = 64k * 32 c-pairs
            int k = e >> 5;
            int cp = e & 31;
            float w0, w1;
            if constexpr (F32) {
                float2 v = *(const float2*)((const float*)wv + (size_t)k * C_ + c0 + 2 * cp);
                w0 = v.x; w1 = v.y;
            } else {
                ushort2 v = *(const ushort2*)((const u16*)wv + (size_t)k * C_ + c0 + 2 * cp);
                w0 = bf2f(v.x); w1 = bf2f(v.y);
            }
            sm.g.wt[(2 * cp) * 68 + k]     = w0;
            sm.g.wt[(2 * cp + 1) * 68 + k] = w1;
        }
#pragma unroll
        for (int i = 0; i < 7; i++) {
            int e = t + 256 * i;          // 0..1791 = 64c * 28 l-quads
            int c = e / 28;
            int lq = e % 28;
            float4 f;
            if constexpr (F32) {
                f = *(const float4*)((const float*)xv + xoff + (size_t)(c0 + c) * L_ + 4 * lq);
            } else {
                ushort4 v = *(const ushort4*)((const u16*)xv + xoff + (size_t)(c0 + c) * L_ + 4 * lq);
                f.x = bf2f(v.x); f.y = bf2f(v.y); f.z = bf2f(v.z); f.w = bf2f(v.w);
            }
            *(float4*)&sm.g.xs[c * 112 + 4 * lq] = f;
        }
        __syncthreads();
#pragma unroll 4
        for (int c = 0; c < 64; c++) {
            float4 w4 = *(const float4*)&sm.g.wt[c * 68 + 4 * ty];
            float wr[4] = {w4.x, w4.y, w4.z, w4.w};
            float xr[7];
#pragma unroll
            for (int j = 0; j < 7; j++) xr[j] = sm.g.xs[c * 112 + tx + 16 * j];
#pragma unroll
            for (int i = 0; i < 4; i++)
#pragma unroll
                for (int j = 0; j < 7; j++) acc[i][j] = fmaf(wr[i], xr[j], acc[i][j]);
        }
        __syncthreads();
    }

#pragma unroll
    for (int i = 0; i < 4; i++)
#pragma unroll
        for (int j = 0; j < 7; j++) sm.sl[(4 * ty + i) * 113 + tx + 16 * j] = acc[i][j];
    __syncthreads();

    if (t < 112) {
        const int l = t;
        float m = -1e30f;
        for (int k = 0; k < 64; k++) m = fmaxf(m, sm.sl[k * 113 + l]);
        float s = 0.f;
        for (int k = 0; k < 64; k++) {
            float e = __expf(sm.sl[k * 113 + l] - m);
            sm.sl[k * 113 + l] = e;
            s += e;
        }
        float inv = 1.f / s;
        for (int k = 0; k < 64; k++) sm.sl[k * 113 + l] *= inv;
    }
    __syncthreads();

    if (t < 64) {
        float s = 0.f;
        for (int l = 0; l < 112; l++) s += sm.sl[t * 113 + l];
        asum_part[((size_t)ln * 7 + lt) * 64 + t] = s;
    }

    // write a as u16 fixed-point: 64 k-rows x 56 l-pairs = 3584 = 14*256
    u16* aout = a_q + (size_t)ln * (K_ * L_) + l0;
#pragma unroll
    for (int i = 0; i < 14; i++) {
        int e = t + 256 * i;              // 0..3583
        int k = e / 56;                   // 0..63
        int lp = e % 56;                  // l = 2*lp, 2*lp+1
        ushort2 qq;
        qq.x = (u16)__float2uint_rn(sm.sl[k * 113 + 2 * lp]     * 65535.f);
        qq.y = (u16)__float2uint_rn(sm.sl[k * 113 + 2 * lp + 1] * 65535.f);
        *(ushort2*)(aout + (size_t)k * L_ + 2 * lp) = qq;
    }
}

// ---------------------------------------------------------------------------
// Kernel B: agg[n,k,c] = sum_l a[n,k,l]*x[n,c,l]  (64k x 128c per block)
// grid (4, Gn). block 256. Thread tile 4k x 8c. l-chunks of 56.
// ---------------------------------------------------------------------------
template <bool F32>
__global__ __launch_bounds__(256) void kB(const void* __restrict__ xv,
                                          const int* __restrict__ flag,
                                          int n0,
                                          const u16* __restrict__ a_q,
                                          float* __restrict__ agg) {
    if (*flag != (F32 ? 1 : 0)) return;
    __shared__ float at[56 * 68];     // at[l][k]
    __shared__ float xt[128 * 60];    // xt[c][l]
    const int t  = threadIdx.x;
    const int ln = blockIdx.y;
    const int n  = n0 + ln;
    const int c0 = blockIdx.x * 128;
    const int tx = t & 15, ty = t >> 4;

    float acc[4][8];
#pragma unroll
    for (int i = 0; i < 4; i++)
#pragma unroll
        for (int j = 0; j < 8; j++) acc[i][j] = 0.f;

    const u16* aq = a_q + (size_t)ln * (K_ * L_);
    const size_t xoff = (size_t)n * (C_ * L_);
    const float dq = 1.f / 65535.f;

    for (int ltile = 0; ltile < 14; ++ltile) {
        const int l0 = ltile * 56;
#pragma unroll
        for (int i = 0; i < 7; i++) {
            int e = t + 256 * i;          // 0..1791 = 64k * 28 l-pairs
            int k = e / 28;
            int lp = e % 28;
            ushort2 qq = *(const ushort2*)(aq + (size_t)k * L_ + l0 + 2 * lp);
            at[(2 * lp) * 68 + k]     = qq.x * dq;
            at[(2 * lp + 1) * 68 + k] = qq.y * dq;
        }
#pragma unroll
        for (int i = 0; i < 7; i++) {
            int e = t + 256 * i;          // 0..1791 = 128c * 14 l-quads
            int c = e / 14;
            int lq = e % 14;
            float4 f;
            if constexpr (F32) {
                f = *(const float4*)((const float*)xv + xoff + (size_t)(c0 + c) * L_ + l0 + 4 * lq);
            } else {
                ushort4 v = *(const ushort4*)((const u16*)xv + xoff + (size_t)(c0 + c) * L_ + l0 + 4 * lq);
                f.x = bf2f(v.x); f.y = bf2f(v.y); f.z = bf2f(v.z); f.w = bf2f(v.w);
            }
            *(float4*)&xt[c * 60 + 4 * lq] = f;
        }
        __syncthreads();
#pragma unroll 4
        for (int l = 0; l < 56; l++) {
            float4 a4 = *(const float4*)&at[l * 68 + 4 * ty];
            float ar[4] = {a4.x, a4.y, a4.z, a4.w};
#pragma unroll
            for (int j = 0; j < 8; j++) {
                float xr = xt[(tx + 16 * j) * 60 + l];
#pragma unroll
                for (int i = 0; i < 4; i++) acc[i][j] = fmaf(ar[i], xr, acc[i][j]);
            }
        }
        __syncthreads();
    }

    float* aggp = agg + (size_t)ln * (K_ * C_) + c0;
#pragma unroll
    for (int i = 0; i < 4; i++)
#pragma unroll
        for (int j = 0; j < 8; j++)
            aggp[(size_t)(4 * ty + i) * C_ + tx + 16 * j] = acc[i][j];
}

// ---------------------------------------------------------------------------
// Kernel C: vlad = agg - asum*cent ; intra-normalize per (n,k) over C;
// global norm is exactly 8 (64 unit rows): out = vlad/(||row||*8).
// OUTPUT DTYPE MATCHES INPUT STORAGE: fp32 path -> float out (the R4 bug was
// writing bf16 into an fp32 buffer); bf16 path -> bf16 out.
// grid (8, Gn). block 256 (4 waves, 2 rows each).
// ---------------------------------------------------------------------------
template <bool F32>
__global__ __launch_bounds__(256) void kC(const float* __restrict__ agg,
                                          const void* __restrict__ centv,
                                          const int* __restrict__ flag,
                                          int n0,
                                          const float* __restrict__ asum_part,
                                          void* __restrict__ outv) {
    if (*flag != (F32 ? 1 : 0)) return;
    __shared__ float asumS[8];
    const int t  = threadIdx.x;
    const int ln = blockIdx.y;
    const int n  = n0 + ln;
    const int k0 = blockIdx.x * 8;
    if (t < 8) {
        float s = 0.f;
        for (int j = 0; j < 7; j++) s += asum_part[((size_t)ln * 7 + j) * 64 + k0 + t];
        asumS[t] = s;
    }
    __syncthreads();
    const int wv = t >> 6;
    const int lane = t & 63;
    for (int r = wv; r < 8; r += 4) {
        const int k = k0 + r;
        const float as = asumS[r];
        const float* ap = agg + (size_t)ln * (K_ * C_) + (size_t)k * C_;
        float v[8];
        float ss = 0.f;
#pragma unroll
        for (int j = 0; j < 8; j++) {
            int c = lane + 64 * j;
            float cv;
            if constexpr (F32) cv = ((const float*)centv)[(size_t)k * C_ + c];
            else               cv = bf2f(((const u16*)centv)[(size_t)k * C_ + c]);
            float val = ap[c] - as * cv;
            v[j] = val;
            ss += val * val;
        }
#pragma unroll
        for (int off = 32; off; off >>= 1) ss += __shfl_xor(ss, off, 64);
        float scale = 1.f / (fmaxf(sqrtf(ss), EPS_) * 8.f);
        const size_t obase = (size_t)n * (K_ * C_) + (size_t)k * C_;
        if constexpr (F32) {
            float* op = (float*)outv;
#pragma unroll
            for (int j = 0; j < 8; j++) op[obase + lane + 64 * j] = v[j] * scale;
        } else {
            u16* op = (u16*)outv;
#pragma unroll
            for (int j = 0; j < 8; j++) op[obase + lane + 64 * j] = f2bf(v[j] * scale);
        }
    }
}

extern "C" void kernel_launch(void* const* d_in, const int* in_sizes, int n_in,
                              void* d_out, int out_size, void* d_ws, size_t ws_size,
                              hipStream_t stream) {
    (void)in_sizes; (void)n_in; (void)out_size;
    const void* x    = d_in[0];   // (64, 512, 28, 28)
    const void* w    = d_in[1];   // (64, 512)
    const void* cent = d_in[2];   // (64, 512)

    // ws layout per group of Gn images:
    //   a_q  u16  [Gn*64*784]  (256B-aligned)
    //   agg  f32  [Gn*64*512]
    //   asum f32  [Gn*7*64]
    //   flag int
    auto ws_need = [](int Gn) -> size_t {
        size_t aq = ((size_t)Gn * 100352 * 2 + 255) / 256 * 256;
        return aq + (size_t)Gn * 131072 * 4 + (size_t)Gn * 448 * 4 + 4;
    };
    int Gn = 1;
    if (ws_size >= ws_need(64)) Gn = 64;
    else if (ws_size >= ws_need(8)) Gn = 8;

    char* base = (char*)d_ws;
    u16*   a_q  = (u16*)base;
    float* agg  = (float*)(base + ((size_t)Gn * 100352 * 2 + 255) / 256 * 256);
    float* asum = agg + (size_t)Gn * 131072;
    int*   flag = (int*)(asum + (size_t)Gn * 448);

    kFlag<<<1, 64, 0, stream>>>((const unsigned*)x, flag);

    for (int n0 = 0; n0 < 64; n0 += Gn) {
        kA<true> <<<dim3(7, Gn), 256, 0, stream>>>(x, w, flag, n0, a_q, asum);
        kA<false><<<dim3(7, Gn), 256, 0, stream>>>(x, w, flag, n0, a_q, asum);
        kB<true> <<<dim3(4, Gn), 256, 0, stream>>>(x, flag, n0, a_q, agg);
        kB<false><<<dim3(4, Gn), 256, 0, stream>>>(x, flag, n0, a_q, agg);
        kC<true> <<<dim3(8, Gn), 256, 0, stream>>>(agg, cent, flag, n0, asum, d_out);
        kC<false><<<dim3(8, Gn), 256, 0, stream>>>(agg, cent, flag, n0, asum, d_out);
    }
}

// Round 6
// 208.585 us; speedup vs baseline: 1.5106x; 1.5106x over previous
//
#include <hip/hip_runtime.h>

#define C_ 512
#define L_ 784
#define K_ 64
#define EPS_ 1e-12f

typedef _Float16 half_t;
typedef _Float16 half8 __attribute__((ext_vector_type(8)));
typedef _Float16 half4 __attribute__((ext_vector_type(4)));
typedef float float4v __attribute__((ext_vector_type(4)));

// ---------------------------------------------------------------------------
// Kernel A (MFMA fp16): logits[k][l] = sum_c w[k][c] * x[n][c][l] for a
// 16-wide l tile, softmax over k, store a (fp16) + partial asum.
// grid (49, 64), block 256 (4 waves). Wave wv owns k-tile [16*wv, 16*wv+16).
// MFMA 16x16x32_f16: A = w (M=k, K=c), B = x (K=c, N=l).
//   A-frag: m=lane&15 -> k,  kk=(lane>>4)*8+j -> c   (8 contiguous c)
//   B-frag: n=lane&15 -> l,  kk=(lane>>4)*8+j -> c   (8 contiguous c)
//   C/D   : row=(lane>>4)*4+reg -> k, col=lane&15 -> l
// ---------------------------------------------------------------------------
__global__ __launch_bounds__(256) void kA(const float* __restrict__ x,
                                          const float* __restrict__ w,
                                          half_t* __restrict__ a_out,     // [64][64][784] fp16
                                          float* __restrict__ asum_part) {// [64][49][64]
    __shared__ half_t wh[64 * 72];   // wh[k][c-chunk 64, stride 72 (144B: 16B-aligned, bank-stride 4 -> ~2-way)]
    __shared__ half_t xh[16 * 72];   // xh[l][c-chunk 64]
    __shared__ float  sl[64 * 17];   // logits/softmax [k][l]
    const int t    = threadIdx.x;
    const int n    = blockIdx.y;
    const int lt   = blockIdx.x;
    const int l0   = lt * 16;
    const int wv   = t >> 6;
    const int lane = t & 63;
    const int m16  = lane & 15;
    const int q    = lane >> 4;

    float4v acc = {0.f, 0.f, 0.f, 0.f};

    const float* xb = x + (size_t)n * (C_ * L_) + l0;

    for (int cc = 0; cc < 8; ++cc) {
        const int c0 = cc * 64;
        // stage w chunk: 64k x 64c, 1024 float4, 4/thread
#pragma unroll
        for (int i = 0; i < 4; i++) {
            int e = t + 256 * i;          // 0..1023
            int k = e >> 4;               // 16 c-quads per k row
            int cq = e & 15;
            float4v f = *(const float4v*)(w + (size_t)k * C_ + c0 + 4 * cq);
            half4 h = { (half_t)f.x, (half_t)f.y, (half_t)f.z, (half_t)f.w };
            *(half4*)&wh[k * 72 + 4 * cq] = h;
        }
        // stage x chunk transposed: 64c x 16l -> xh[l][c]; 256 float4, 1/thread
        {
            int c  = t >> 2;              // 0..63
            int lq = t & 3;               // l-quad
            float4v f = *(const float4v*)(xb + (size_t)(c0 + c) * L_ + 4 * lq);
            xh[(4 * lq + 0) * 72 + c] = (half_t)f.x;
            xh[(4 * lq + 1) * 72 + c] = (half_t)f.y;
            xh[(4 * lq + 2) * 72 + c] = (half_t)f.z;
            xh[(4 * lq + 3) * 72 + c] = (half_t)f.w;
        }
        __syncthreads();
#pragma unroll
        for (int s = 0; s < 2; s++) {     // two K=32 substeps cover the 64-c chunk
            half8 A = *(const half8*)&wh[(wv * 16 + m16) * 72 + 32 * s + 8 * q];
            half8 B = *(const half8*)&xh[m16 * 72 + 32 * s + 8 * q];
            acc = __builtin_amdgcn_mfma_f32_16x16x32_f16(A, B, acc, 0, 0, 0);
        }
        __syncthreads();
    }

    // D -> sl[k][l]
#pragma unroll
    for (int r = 0; r < 4; r++)
        sl[(wv * 16 + q * 4 + r) * 17 + m16] = acc[r];
    __syncthreads();

    // softmax over k, one l-column per thread (16 active)
    if (t < 16) {
        const int l = t;
        float mx = -1e30f;
        for (int k = 0; k < 64; k++) mx = fmaxf(mx, sl[k * 17 + l]);
        float s = 0.f;
        for (int k = 0; k < 64; k++) {
            float e = __expf(sl[k * 17 + l] - mx);
            sl[k * 17 + l] = e;
            s += e;
        }
        float inv = 1.f / s;
        for (int k = 0; k < 64; k++) sl[k * 17 + l] *= inv;
    }
    __syncthreads();

    // partial asum per k over this l-tile
    if (t < 64) {
        float s = 0.f;
        for (int l = 0; l < 16; l++) s += sl[t * 17 + l];
        asum_part[((size_t)n * 49 + lt) * 64 + t] = s;
    }

    // a_out fp16: 64k x 16l = 1024 halfs, 4/thread (8-B stores)
    {
        int k = t >> 2, lq = t & 3;
        half4 h = { (half_t)sl[k * 17 + 4 * lq],     (half_t)sl[k * 17 + 4 * lq + 1],
                    (half_t)sl[k * 17 + 4 * lq + 2], (half_t)sl[k * 17 + 4 * lq + 3] };
        *(half4*)(a_out + (size_t)n * (K_ * L_) + (size_t)k * L_ + l0 + 4 * lq) = h;
    }
}

// ---------------------------------------------------------------------------
// Kernel B (MFMA fp16): agg[k][c] = sum_l a[k][l] * x[c][l], c-tile 64.
// grid (8, 64), block 256 (4 waves). Wave wv -> k-tile; 4 c-subtiles each.
// A = a (M=k, K=l), B = x^T (K=l, N=c). l-chunks of 32 (25 chunks, tail 16
// zero-padded; 784 = 24*32 + 16).
// ---------------------------------------------------------------------------
__global__ __launch_bounds__(256) void kB(const float* __restrict__ x,
                                          const half_t* __restrict__ a_in,  // [64][64][784] fp16
                                          float* __restrict__ agg) {        // [64][64][512]
    __shared__ half_t ah[64 * 40];   // ah[k][l-chunk 32, stride 40 (80B: 16B-aligned, bank-stride 20 -> 2-way)]
    __shared__ half_t xh[64 * 40];   // xh[c][l-chunk 32]
    const int t    = threadIdx.x;
    const int n    = blockIdx.y;
    const int c0   = blockIdx.x * 64;
    const int wv   = t >> 6;
    const int lane = t & 63;
    const int m16  = lane & 15;
    const int q    = lane >> 4;

    float4v acc[4] = {{0.f,0.f,0.f,0.f},{0.f,0.f,0.f,0.f},{0.f,0.f,0.f,0.f},{0.f,0.f,0.f,0.f}};

    const float*  xb = x   + (size_t)n * (C_ * L_);
    const half_t* ab = a_in + (size_t)n * (K_ * L_);

    for (int ltile = 0; ltile < 25; ++ltile) {
        const int l0 = ltile * 32;
        // stage a: 64k x 32l halfs, 8 halfs/thread (16-B loads/stores)
        {
            int k = t >> 2, lq8 = t & 3;   // 4 octets of l per k
            int l = l0 + 8 * lq8;
            half8 h;
            if (l < L_) h = *(const half8*)(ab + (size_t)k * L_ + l);
            else        h = (half8)(half_t)0.f;
            *(half8*)&ah[k * 40 + 8 * lq8] = h;
        }
        // stage x: 64c x 32l fp32 -> fp16, 512 float4, 2/thread
#pragma unroll
        for (int i = 0; i < 2; i++) {
            int e = t + 256 * i;           // 0..511
            int c = e >> 3, lq = e & 7;
            int l = l0 + 4 * lq;
            half4 h;
            if (l < L_) {
                float4v f = *(const float4v*)(xb + (size_t)(c0 + c) * L_ + l);
                h = half4{ (half_t)f.x, (half_t)f.y, (half_t)f.z, (half_t)f.w };
            } else {
                h = half4{ (half_t)0.f, (half_t)0.f, (half_t)0.f, (half_t)0.f };
            }
            *(half4*)&xh[c * 40 + 4 * lq] = h;
        }
        __syncthreads();
        {
            half8 A = *(const half8*)&ah[(wv * 16 + m16) * 40 + 8 * q];
#pragma unroll
            for (int ct = 0; ct < 4; ct++) {
                half8 B = *(const half8*)&xh[(ct * 16 + m16) * 40 + 8 * q];
                acc[ct] = __builtin_amdgcn_mfma_f32_16x16x32_f16(A, B, acc[ct], 0, 0, 0);
            }
        }
        __syncthreads();
    }

    float* ap = agg + (size_t)n * (K_ * C_);
#pragma unroll
    for (int ct = 0; ct < 4; ct++)
#pragma unroll
        for (int r = 0; r < 4; r++)
            ap[(size_t)(wv * 16 + q * 4 + r) * C_ + c0 + ct * 16 + m16] = acc[ct][r];
}

// ---------------------------------------------------------------------------
// Kernel C: vlad = agg - asum*cent ; intra-normalize per (n,k) over C;
// global norm is exactly 8 (64 unit rows): out = vlad/(||row||*8). fp32 out.
// grid (8, 64), block 256 (4 waves, 2 rows each).
// ---------------------------------------------------------------------------
__global__ __launch_bounds__(256) void kC(const float* __restrict__ agg,
                                          const float* __restrict__ cent,
                                          const float* __restrict__ asum_part,
                                          float* __restrict__ out) {
    __shared__ float asumS[8];
    const int t  = threadIdx.x;
    const int n  = blockIdx.y;
    const int k0 = blockIdx.x * 8;
    if (t < 8) {
        float s = 0.f;
        for (int j = 0; j < 49; j++) s += asum_part[((size_t)n * 49 + j) * 64 + k0 + t];
        asumS[t] = s;
    }
    __syncthreads();
    const int wv = t >> 6;
    const int lane = t & 63;
    for (int r = wv; r < 8; r += 4) {
        const int k = k0 + r;
        const float as = asumS[r];
        const float* ap = agg + (size_t)n * (K_ * C_) + (size_t)k * C_;
        const float* cp = cent + (size_t)k * C_;
        float v[8];
        float ss = 0.f;
#pragma unroll
        for (int j = 0; j < 8; j++) {
            int c = lane + 64 * j;
            float val = ap[c] - as * cp[c];
            v[j] = val;
            ss += val * val;
        }
#pragma unroll
        for (int off = 32; off; off >>= 1) ss += __shfl_xor(ss, off, 64);
        float scale = 1.f / (fmaxf(sqrtf(ss), EPS_) * 8.f);
        float* op = out + (size_t)n * (K_ * C_) + (size_t)k * C_;
#pragma unroll
        for (int j = 0; j < 8; j++) op[lane + 64 * j] = v[j] * scale;
    }
}

extern "C" void kernel_launch(void* const* d_in, const int* in_sizes, int n_in,
                              void* d_out, int out_size, void* d_ws, size_t ws_size,
                              hipStream_t stream) {
    (void)in_sizes; (void)n_in; (void)out_size; (void)ws_size;
    const float* x    = (const float*)d_in[0];   // (64, 512, 28, 28) fp32
    const float* w    = (const float*)d_in[1];   // (64, 512) fp32
    const float* cent = (const float*)d_in[2];   // (64, 512) fp32
    float* out = (float*)d_out;                  // (64, 32768) fp32

    // ws: a fp16 [64*64*784] = 6.42 MB ; agg f32 [64*64*512] = 8.39 MB ;
    //     asum f32 [64*49*64] = 0.80 MB.  Total 15.6 MB (R5 ran Gn=64 ->
    //     ws_size >= 46 MB known-good).
    char* base = (char*)d_ws;
    half_t* a    = (half_t*)base;
    float*  agg  = (float*)(base + ((size_t)K_ * L_ * 64 * 2 + 255) / 256 * 256);
    float*  asum = agg + (size_t)64 * K_ * C_;

    kA<<<dim3(49, 64), 256, 0, stream>>>(x, w, a, asum);
    kB<<<dim3(8, 64),  256, 0, stream>>>(x, a, agg);
    kC<<<dim3(8, 64),  256, 0, stream>>>(agg, cent, asum, out);
}